// Round 2
// baseline (671.596 us; speedup 1.0000x reference)
//
#include <hip/hip_runtime.h>

// HIGNN edge-MLP fused kernel, round 2.
// R1 finding: device-scope fp32 atomicAdd writes through the fabric at 32 B/op
// (WRITE_SIZE == n_atomics*32B exactly) -> 150 MB traffic for a 1.2 MB output,
// bound at ~18 G atomics/s. Fix: 8 per-XCD private output copies in d_ws,
// workgroup-scope atomics (execute in the local XCD's TCC/L2, write-back,
// no fabric write-through), then a cheap reduce kernel sums the 8 copies.

constexpr int HIDDEN = 64;
constexpr int NXCC = 8;

__device__ __forceinline__ int xcc_id() {
    int x;
    asm volatile("s_getreg_b32 %0, hwreg(HW_REG_XCC_ID)" : "=s"(x));
    return x & (NXCC - 1);
}

template <int DIN, int KPT, bool PART>
__global__ __launch_bounds__(256) void edge_mlp_kernel(
    const float* __restrict__ x,
    const int* __restrict__ edges, long long E,
    const float* __restrict__ attr,
    const float* __restrict__ W1, const float* __restrict__ b1,
    const float* __restrict__ W2, const float* __restrict__ b2,
    float* __restrict__ outbuf, int nout)
{
    float* o_base;
    if constexpr (PART) {
        // each XCD accumulates into its private copy; XCD-local L2 is the
        // atomic execution point for workgroup-scope atomics -> correct.
        o_base = outbuf + (size_t)xcc_id() * (size_t)nout;
    } else {
        o_base = outbuf;
    }

    const int tid = threadIdx.x;
    const long long base = (long long)blockIdx.x * (blockDim.x * KPT) + tid;

    float d[KPT][DIN];
    float a[KPT][3];
    int   dst[KPT];
    bool  valid[KPT];

    #pragma unroll
    for (int u = 0; u < KPT; ++u) {
        long long e = base + (long long)u * blockDim.x;
        valid[u] = (e < E);
        long long ee = valid[u] ? e : 0;   // clamp: compute garbage, skip store
        if constexpr (DIN == 3) {
            int s = edges[ee];
            int t = edges[E + ee];
            dst[u] = t;
            #pragma unroll
            for (int c = 0; c < 3; ++c)
                d[u][c] = x[3 * (long long)s + c] - x[3 * (long long)t + c];
        } else {
            int j = edges[ee];
            int k = edges[E + ee];
            int i = edges[2 * E + ee];
            dst[u] = i;
            #pragma unroll
            for (int c = 0; c < 3; ++c) {
                float xj = x[3 * (long long)j + c];
                float xk = x[3 * (long long)k + c];
                float xi = x[3 * (long long)i + c];
                d[u][c]     = xk - xj;
                d[u][3 + c] = xi - xk;
            }
        }
        #pragma unroll
        for (int c = 0; c < 3; ++c) a[u][c] = attr[3 * ee + c];
    }

    float acc[KPT][9];
    #pragma unroll
    for (int u = 0; u < KPT; ++u)
        #pragma unroll
        for (int i = 0; i < 9; ++i) acc[u][i] = b2[i];

    #pragma unroll 4
    for (int hh = 0; hh < HIDDEN; ++hh) {
        const float bb = b1[hh];
        float w1r[DIN];
        #pragma unroll
        for (int r = 0; r < DIN; ++r) w1r[r] = W1[r * HIDDEN + hh];
        float w2r[9];
        #pragma unroll
        for (int i = 0; i < 9; ++i) w2r[i] = W2[hh * 9 + i];

        #pragma unroll
        for (int u = 0; u < KPT; ++u) {
            float pre = bb;
            #pragma unroll
            for (int r = 0; r < DIN; ++r) pre = fmaf(d[u][r], w1r[r], pre);
            const float h = fmaxf(pre, 0.0f);
            #pragma unroll
            for (int i = 0; i < 9; ++i) acc[u][i] = fmaf(h, w2r[i], acc[u][i]);
        }
    }

    #pragma unroll
    for (int u = 0; u < KPT; ++u) {
        if (!valid[u]) continue;
        float* o = o_base + 3 * (long long)dst[u];
        #pragma unroll
        for (int i = 0; i < 3; ++i) {
            float y = fmaf(acc[u][3 * i + 0], a[u][0],
                      fmaf(acc[u][3 * i + 1], a[u][1],
                           acc[u][3 * i + 2] * a[u][2]));
            if constexpr (PART) {
                __hip_atomic_fetch_add(&o[i], y, __ATOMIC_RELAXED,
                                       __HIP_MEMORY_SCOPE_WORKGROUP);
            } else {
                atomicAdd(&o[i], y);
            }
        }
    }
}

__global__ __launch_bounds__(256) void reduce_partials(
    const float4* __restrict__ p, float4* __restrict__ out,
    int n4, long long stride4)
{
    int i = blockIdx.x * blockDim.x + threadIdx.x;
    if (i >= n4) return;
    float4 s = p[i];
    #pragma unroll
    for (int c = 1; c < NXCC; ++c) {
        float4 v = p[(long long)c * stride4 + i];
        s.x += v.x; s.y += v.y; s.z += v.z; s.w += v.w;
    }
    out[i] = s;
}

// scalar tail for out_size not divisible by 4 (defensive)
__global__ void reduce_partials_tail(const float* __restrict__ p,
                                     float* __restrict__ out,
                                     int start, int n, long long stride)
{
    int i = start + blockIdx.x * blockDim.x + threadIdx.x;
    if (i >= n) return;
    float s = 0.f;
    #pragma unroll
    for (int c = 0; c < NXCC; ++c) s += p[(long long)c * stride + i];
    out[i] = s;
}

extern "C" void kernel_launch(void* const* d_in, const int* in_sizes, int n_in,
                              void* d_out, int out_size, void* d_ws, size_t ws_size,
                              hipStream_t stream)
{
    const float* x  = (const float*)d_in[0];
    const int*   e2 = (const int*)d_in[1];
    const int*   e3 = (const int*)d_in[2];
    const int*   es = (const int*)d_in[3];
    const float* a2 = (const float*)d_in[5];
    const float* a3 = (const float*)d_in[6];
    const float* as = (const float*)d_in[7];
    const float* W1_2b = (const float*)d_in[9];
    const float* b1_2b = (const float*)d_in[10];
    const float* W2_2b = (const float*)d_in[11];
    const float* b2_2b = (const float*)d_in[12];
    const float* W1_3b = (const float*)d_in[13];
    const float* b1_3b = (const float*)d_in[14];
    const float* W2_3b = (const float*)d_in[15];
    const float* b2_3b = (const float*)d_in[16];
    const float* W1_s  = (const float*)d_in[17];
    const float* b1_s  = (const float*)d_in[18];
    const float* W2_s  = (const float*)d_in[19];
    const float* b2_s  = (const float*)d_in[20];

    const long long E2 = in_sizes[1] / 2;
    const long long E3 = in_sizes[2] / 3;
    const long long ES = in_sizes[3] / 2;

    float* out = (float*)d_out;

    constexpr int BLK = 256;
    constexpr int KPT = 4;
    const long long per_blk = (long long)BLK * KPT;
    int g2 = (int)((E2 + per_blk - 1) / per_blk);
    int g3 = (int)((E3 + per_blk - 1) / per_blk);
    int gs = (int)((ES + per_blk - 1) / per_blk);

    const size_t need = (size_t)NXCC * (size_t)out_size * sizeof(float);

    if (ws_size >= need) {
        // --- per-XCD privatized path ---
        float* part = (float*)d_ws;
        hipMemsetAsync(part, 0, need, stream);

        if (g2 > 0)
            edge_mlp_kernel<3, KPT, true><<<g2, BLK, 0, stream>>>(
                x, e2, E2, a2, W1_2b, b1_2b, W2_2b, b2_2b, part, out_size);
        if (g3 > 0)
            edge_mlp_kernel<6, KPT, true><<<g3, BLK, 0, stream>>>(
                x, e3, E3, a3, W1_3b, b1_3b, W2_3b, b2_3b, part, out_size);
        if (gs > 0)
            edge_mlp_kernel<3, KPT, true><<<gs, BLK, 0, stream>>>(
                x, es, ES, as, W1_s, b1_s, W2_s, b2_s, part, out_size);

        int n4 = out_size / 4;
        int tail = out_size - n4 * 4;
        if (n4 > 0)
            reduce_partials<<<(n4 + BLK - 1) / BLK, BLK, 0, stream>>>(
                (const float4*)part, (float4*)out, n4, (long long)out_size / 4);
        if (tail > 0)
            reduce_partials_tail<<<1, 64, 0, stream>>>(
                part, out, n4 * 4, out_size, (long long)out_size);
    } else {
        // --- fallback: direct device-scope atomics (R1 behavior) ---
        hipMemsetAsync(out, 0, (size_t)out_size * sizeof(float), stream);
        if (g2 > 0)
            edge_mlp_kernel<3, KPT, false><<<g2, BLK, 0, stream>>>(
                x, e2, E2, a2, W1_2b, b1_2b, W2_2b, b2_2b, out, out_size);
        if (g3 > 0)
            edge_mlp_kernel<6, KPT, false><<<g3, BLK, 0, stream>>>(
                x, e3, E3, a3, W1_3b, b1_3b, W2_3b, b2_3b, out, out_size);
        if (gs > 0)
            edge_mlp_kernel<3, KPT, false><<<gs, BLK, 0, stream>>>(
                x, es, ES, as, W1_s, b1_s, W2_s, b2_s, out, out_size);
    }
}

// Round 3
// 380.509 us; speedup vs baseline: 1.7650x; 1.7650x over previous
//
#include <hip/hip_runtime.h>

// HIGNN, round 3: bucketed two-phase scatter.
// R1/R2 finding: fp32 global atomicAdd on gfx950 writes through the fabric at
// 32 B/op (WRITE_SIZE == n_atomics*32B exactly), ~18 G atomics/s, regardless
// of scope or XCD privatization. 9.9M atomics -> 670 us, all in the scatter.
// Fix: never do per-edge global fp32 atomics.
//   Phase 1: per edge set, fused gather+MLP (once per edge), then append a
//            float4 record (y0,y1,y2,dst-as-bits) into bucket dst>>9 in d_ws.
//            Append = per-block LDS histogram -> ONE int reservation atomic
//            per (block,bucket) (~410k total) -> plain 16B stores.
//   Phase 2: one block per bucket; LDS-accumulate its records (LDS atomics),
//            plain stores to out. All 3 edge sets share one record pool.

constexpr int HIDDEN = 64;
constexpr int NB_MAX = 256;      // LDS histogram bins (>= nbuckets)
constexpr int NPB_SHIFT = 9;     // 512 nodes per bucket
constexpr int NPB = 1 << NPB_SHIFT;

// ---------------- Phase 1: edge MLP + bucket append ----------------
template <int DIN>
__global__ __launch_bounds__(256) void p1_edge_kernel(
    const float* __restrict__ x,
    const int* __restrict__ edges, long long E,
    const float* __restrict__ attr,
    const float* __restrict__ W1, const float* __restrict__ b1,
    const float* __restrict__ W2, const float* __restrict__ b2,
    float4* __restrict__ records, int* __restrict__ gcount, int cap)
{
    __shared__ int s_hist[NB_MAX];
    __shared__ int s_base[NB_MAX];
    __shared__ int s_rank[NB_MAX];

    const int tid = threadIdx.x;
    const long long span = (E + gridDim.x - 1) / gridDim.x;
    const long long lo = (long long)blockIdx.x * span;
    const long long hi = (lo + span < E) ? (lo + span) : E;

    for (int i = tid; i < NB_MAX; i += 256) { s_hist[i] = 0; s_rank[i] = 0; }
    __syncthreads();

    // pass A: histogram of destinations (cheap re-read, L2-resident)
    const long long dstrow = (DIN == 3) ? E : 2 * E;
    for (long long e = lo + tid; e < hi; e += 256) {
        int d = edges[dstrow + e];
        atomicAdd(&s_hist[d >> NPB_SHIFT], 1);
    }
    __syncthreads();

    // reserve contiguous slots per bucket: one global atomic per nonempty bin
    for (int i = tid; i < NB_MAX; i += 256) {
        int h = s_hist[i];
        s_base[i] = (h > 0) ? atomicAdd(&gcount[i], h) : 0;
    }
    __syncthreads();

    // pass B: MLP + append, tiles of 1024 edges (4/thread)
    constexpr int KPT = 4;
    for (long long t0 = lo; t0 < hi; t0 += 256 * KPT) {
        float d[KPT][DIN];
        float a[KPT][3];
        int   dst[KPT];
        bool  valid[KPT];

        #pragma unroll
        for (int u = 0; u < KPT; ++u) {
            long long e = t0 + (long long)u * 256 + tid;
            valid[u] = (e < hi);
            long long ee = valid[u] ? e : lo;
            if constexpr (DIN == 3) {
                int s = edges[ee];
                int t = edges[E + ee];
                dst[u] = t;
                #pragma unroll
                for (int c = 0; c < 3; ++c)
                    d[u][c] = x[3 * (long long)s + c] - x[3 * (long long)t + c];
            } else {
                int j = edges[ee];
                int k = edges[E + ee];
                int i = edges[2 * E + ee];
                dst[u] = i;
                #pragma unroll
                for (int c = 0; c < 3; ++c) {
                    float xj = x[3 * (long long)j + c];
                    float xk = x[3 * (long long)k + c];
                    float xi = x[3 * (long long)i + c];
                    d[u][c]     = xk - xj;
                    d[u][3 + c] = xi - xk;
                }
            }
            #pragma unroll
            for (int c = 0; c < 3; ++c) a[u][c] = attr[3 * ee + c];
        }

        float acc[KPT][9];
        #pragma unroll
        for (int u = 0; u < KPT; ++u)
            #pragma unroll
            for (int i = 0; i < 9; ++i) acc[u][i] = b2[i];

        #pragma unroll 4
        for (int hh = 0; hh < HIDDEN; ++hh) {
            const float bb = b1[hh];
            float w1r[DIN];
            #pragma unroll
            for (int r = 0; r < DIN; ++r) w1r[r] = W1[r * HIDDEN + hh];
            float w2r[9];
            #pragma unroll
            for (int i = 0; i < 9; ++i) w2r[i] = W2[hh * 9 + i];
            #pragma unroll
            for (int u = 0; u < KPT; ++u) {
                float pre = bb;
                #pragma unroll
                for (int r = 0; r < DIN; ++r) pre = fmaf(d[u][r], w1r[r], pre);
                const float h = fmaxf(pre, 0.0f);
                #pragma unroll
                for (int i = 0; i < 9; ++i) acc[u][i] = fmaf(h, w2r[i], acc[u][i]);
            }
        }

        #pragma unroll
        for (int u = 0; u < KPT; ++u) {
            if (!valid[u]) continue;
            float y0 = fmaf(acc[u][0], a[u][0], fmaf(acc[u][1], a[u][1], acc[u][2] * a[u][2]));
            float y1 = fmaf(acc[u][3], a[u][0], fmaf(acc[u][4], a[u][1], acc[u][5] * a[u][2]));
            float y2 = fmaf(acc[u][6], a[u][0], fmaf(acc[u][7], a[u][1], acc[u][8] * a[u][2]));
            int b = dst[u] >> NPB_SHIFT;
            int r = atomicAdd(&s_rank[b], 1);            // LDS, fast
            int slot = s_base[b] + r;
            if (slot < cap)                              // ~12-sigma safety clamp
                records[(size_t)b * cap + slot] =
                    make_float4(y0, y1, y2, __int_as_float(dst[u]));
        }
    }
}

// ---------------- Phase 2: per-bucket LDS reduction ----------------
__global__ __launch_bounds__(256) void p2_reduce(
    const float4* __restrict__ records, const int* __restrict__ gcount,
    int cap, int n_nodes, float* __restrict__ out)
{
    __shared__ float s_acc[NPB * 3];   // 6 KB
    const int b = blockIdx.x;
    const int tid = threadIdx.x;

    for (int i = tid; i < NPB * 3; i += 256) s_acc[i] = 0.0f;
    __syncthreads();

    int cnt = gcount[b];
    if (cnt > cap) cnt = cap;
    const float4* rb = records + (size_t)b * cap;
    for (int i = tid; i < cnt; i += 256) {
        float4 r = rb[i];
        int loc = __float_as_int(r.w) - (b << NPB_SHIFT);
        atomicAdd(&s_acc[loc * 3 + 0], r.x);
        atomicAdd(&s_acc[loc * 3 + 1], r.y);
        atomicAdd(&s_acc[loc * 3 + 2], r.z);
    }
    __syncthreads();

    const int start = (b << NPB_SHIFT) * 3;
    const int end = min(n_nodes, (b + 1) << NPB_SHIFT) * 3;
    for (int i = start + tid; i < end; i += 256)
        out[i] = s_acc[i - start];
}

// ---------------- Fallback (R1): direct device atomics ----------------
template <int DIN, int KPT>
__global__ __launch_bounds__(256) void edge_mlp_atomic(
    const float* __restrict__ x,
    const int* __restrict__ edges, long long E,
    const float* __restrict__ attr,
    const float* __restrict__ W1, const float* __restrict__ b1,
    const float* __restrict__ W2, const float* __restrict__ b2,
    float* __restrict__ out)
{
    const int tid = threadIdx.x;
    const long long base = (long long)blockIdx.x * (blockDim.x * KPT) + tid;
    float d[KPT][DIN]; float a[KPT][3]; int dst[KPT]; bool valid[KPT];
    #pragma unroll
    for (int u = 0; u < KPT; ++u) {
        long long e = base + (long long)u * blockDim.x;
        valid[u] = (e < E);
        long long ee = valid[u] ? e : 0;
        if constexpr (DIN == 3) {
            int s = edges[ee]; int t = edges[E + ee]; dst[u] = t;
            #pragma unroll
            for (int c = 0; c < 3; ++c)
                d[u][c] = x[3 * (long long)s + c] - x[3 * (long long)t + c];
        } else {
            int j = edges[ee]; int k = edges[E + ee]; int i = edges[2 * E + ee];
            dst[u] = i;
            #pragma unroll
            for (int c = 0; c < 3; ++c) {
                float xj = x[3 * (long long)j + c];
                float xk = x[3 * (long long)k + c];
                float xi = x[3 * (long long)i + c];
                d[u][c] = xk - xj; d[u][3 + c] = xi - xk;
            }
        }
        #pragma unroll
        for (int c = 0; c < 3; ++c) a[u][c] = attr[3 * ee + c];
    }
    float acc[KPT][9];
    #pragma unroll
    for (int u = 0; u < KPT; ++u)
        #pragma unroll
        for (int i = 0; i < 9; ++i) acc[u][i] = b2[i];
    #pragma unroll 4
    for (int hh = 0; hh < HIDDEN; ++hh) {
        const float bb = b1[hh];
        float w1r[DIN];
        #pragma unroll
        for (int r = 0; r < DIN; ++r) w1r[r] = W1[r * HIDDEN + hh];
        float w2r[9];
        #pragma unroll
        for (int i = 0; i < 9; ++i) w2r[i] = W2[hh * 9 + i];
        #pragma unroll
        for (int u = 0; u < KPT; ++u) {
            float pre = bb;
            #pragma unroll
            for (int r = 0; r < DIN; ++r) pre = fmaf(d[u][r], w1r[r], pre);
            const float h = fmaxf(pre, 0.0f);
            #pragma unroll
            for (int i = 0; i < 9; ++i) acc[u][i] = fmaf(h, w2r[i], acc[u][i]);
        }
    }
    #pragma unroll
    for (int u = 0; u < KPT; ++u) {
        if (!valid[u]) continue;
        float* o = out + 3 * (long long)dst[u];
        #pragma unroll
        for (int i = 0; i < 3; ++i) {
            float y = fmaf(acc[u][3 * i + 0], a[u][0],
                      fmaf(acc[u][3 * i + 1], a[u][1],
                           acc[u][3 * i + 2] * a[u][2]));
            atomicAdd(&o[i], y);
        }
    }
}

extern "C" void kernel_launch(void* const* d_in, const int* in_sizes, int n_in,
                              void* d_out, int out_size, void* d_ws, size_t ws_size,
                              hipStream_t stream)
{
    const float* x  = (const float*)d_in[0];
    const int*   e2 = (const int*)d_in[1];
    const int*   e3 = (const int*)d_in[2];
    const int*   es = (const int*)d_in[3];
    const float* a2 = (const float*)d_in[5];
    const float* a3 = (const float*)d_in[6];
    const float* as = (const float*)d_in[7];
    const float* W1_2b = (const float*)d_in[9];
    const float* b1_2b = (const float*)d_in[10];
    const float* W2_2b = (const float*)d_in[11];
    const float* b2_2b = (const float*)d_in[12];
    const float* W1_3b = (const float*)d_in[13];
    const float* b1_3b = (const float*)d_in[14];
    const float* W2_3b = (const float*)d_in[15];
    const float* b2_3b = (const float*)d_in[16];
    const float* W1_s  = (const float*)d_in[17];
    const float* b1_s  = (const float*)d_in[18];
    const float* W2_s  = (const float*)d_in[19];
    const float* b2_s  = (const float*)d_in[20];

    const long long E2 = in_sizes[1] / 2;
    const long long E3 = in_sizes[2] / 3;
    const long long ES = in_sizes[3] / 2;
    const long long Etot = E2 + E3 + ES;
    const int n_nodes = out_size / 3;
    const int nbuckets = (n_nodes + NPB - 1) >> NPB_SHIFT;

    float* out = (float*)d_out;

    // workspace layout: [int gcount[256] (1KB, pad to 4KB)] [float4 records]
    // capacity: per-bucket load is Binomial(Etot, 1/nbuckets); mean + ~12 sigma.
    long long mean_per_bucket = (Etot + nbuckets - 1) / nbuckets;
    long long min_cap = mean_per_bucket + 1600;
    long long cap_avail = ((long long)ws_size - 4096) / ((long long)nbuckets * 16);

    if (nbuckets <= NB_MAX && cap_avail >= min_cap) {
        int cap = (int)((cap_avail < min_cap + 4096) ? cap_avail : (min_cap + 4096));
        int* gcount = (int*)d_ws;
        float4* records = (float4*)((char*)d_ws + 4096);

        hipMemsetAsync(gcount, 0, NB_MAX * sizeof(int), stream);

        if (E2 > 0)
            p1_edge_kernel<3><<<768, 256, 0, stream>>>(
                x, e2, E2, a2, W1_2b, b1_2b, W2_2b, b2_2b, records, gcount, cap);
        if (E3 > 0)
            p1_edge_kernel<6><<<768, 256, 0, stream>>>(
                x, e3, E3, a3, W1_3b, b1_3b, W2_3b, b2_3b, records, gcount, cap);
        if (ES > 0)
            p1_edge_kernel<3><<<96, 256, 0, stream>>>(
                x, es, ES, as, W1_s, b1_s, W2_s, b2_s, records, gcount, cap);

        p2_reduce<<<nbuckets, 256, 0, stream>>>(records, gcount, cap, n_nodes, out);
    } else {
        // fallback: R1 direct-atomic path
        hipMemsetAsync(out, 0, (size_t)out_size * sizeof(float), stream);
        constexpr int BLK = 256, KPT = 4;
        const long long per_blk = (long long)BLK * KPT;
        int g2 = (int)((E2 + per_blk - 1) / per_blk);
        int g3 = (int)((E3 + per_blk - 1) / per_blk);
        int gs = (int)((ES + per_blk - 1) / per_blk);
        if (g2 > 0)
            edge_mlp_atomic<3, KPT><<<g2, BLK, 0, stream>>>(
                x, e2, E2, a2, W1_2b, b1_2b, W2_2b, b2_2b, out);
        if (g3 > 0)
            edge_mlp_atomic<6, KPT><<<g3, BLK, 0, stream>>>(
                x, e3, E3, a3, W1_3b, b1_3b, W2_3b, b2_3b, out);
        if (gs > 0)
            edge_mlp_atomic<3, KPT><<<gs, BLK, 0, stream>>>(
                x, es, ES, as, W1_s, b1_s, W2_s, b2_s, out);
    }
}

// Round 4
// 350.251 us; speedup vs baseline: 1.9175x; 1.0864x over previous
//
#include <hip/hip_runtime.h>

// HIGNN, round 4: same two-phase bucketed scatter as R3, occupancy-fixed.
// R3 post-mortem: p1 grid (768 x 256thr) capped occupancy at 12 waves/CU
// (25% measured) -> 50% VALU idle. p2 used 196 blocks = 6% occupancy.
// R4: p1 = 1024-thread blocks, KPT=2 (tile 2048 == span), grid ceil(E/2048)
//     -> 32 waves/CU. p2 = S=4 sub-blocks per bucket -> partial LDS tiles ->
//     plain stores -> tiny float4 reduce. Zero global fp32 atomics.

constexpr int HIDDEN = 64;
constexpr int NB_MAX = 256;      // LDS histogram bins (>= nbuckets)
constexpr int NPB_SHIFT = 9;     // 512 nodes per bucket
constexpr int NPB = 1 << NPB_SHIFT;
constexpr int SSPLIT = 4;        // p2 sub-blocks per bucket
constexpr int TILE_F = NPB * 3;  // floats per bucket tile (1536)
constexpr int TILE_F4 = TILE_F / 4;

// ---------------- Phase 1: edge MLP + bucket append ----------------
template <int DIN>
__global__ __launch_bounds__(1024) void p1_edge_kernel(
    const float* __restrict__ x,
    const int* __restrict__ edges, long long E,
    const float* __restrict__ attr,
    const float* __restrict__ W1, const float* __restrict__ b1,
    const float* __restrict__ W2, const float* __restrict__ b2,
    float4* __restrict__ records, int* __restrict__ gcount, int cap)
{
    constexpr int BLK = 1024;
    constexpr int KPT = 2;

    __shared__ int s_hist[NB_MAX];
    __shared__ int s_base[NB_MAX];
    __shared__ int s_rank[NB_MAX];

    const int tid = threadIdx.x;
    const long long span = (E + gridDim.x - 1) / gridDim.x;
    const long long lo = (long long)blockIdx.x * span;
    const long long hi = (lo + span < E) ? (lo + span) : E;

    for (int i = tid; i < NB_MAX; i += BLK) { s_hist[i] = 0; s_rank[i] = 0; }
    __syncthreads();

    // pass A: histogram of destinations
    const long long dstrow = (DIN == 3) ? E : 2 * E;
    for (long long e = lo + tid; e < hi; e += BLK) {
        int d = edges[dstrow + e];
        atomicAdd(&s_hist[d >> NPB_SHIFT], 1);
    }
    __syncthreads();

    // reserve contiguous slots: one global int atomic per nonempty bin
    for (int i = tid; i < NB_MAX; i += BLK) {
        int h = s_hist[i];
        s_base[i] = (h > 0) ? atomicAdd(&gcount[i], h) : 0;
    }
    __syncthreads();

    // pass B: MLP + append
    for (long long t0 = lo; t0 < hi; t0 += BLK * KPT) {
        float d[KPT][DIN];
        float a[KPT][3];
        int   dst[KPT];
        bool  valid[KPT];

        #pragma unroll
        for (int u = 0; u < KPT; ++u) {
            long long e = t0 + (long long)u * BLK + tid;
            valid[u] = (e < hi);
            long long ee = valid[u] ? e : lo;
            if constexpr (DIN == 3) {
                int s = edges[ee];
                int t = edges[E + ee];
                dst[u] = t;
                #pragma unroll
                for (int c = 0; c < 3; ++c)
                    d[u][c] = x[3 * (long long)s + c] - x[3 * (long long)t + c];
            } else {
                int j = edges[ee];
                int k = edges[E + ee];
                int i = edges[2 * E + ee];
                dst[u] = i;
                #pragma unroll
                for (int c = 0; c < 3; ++c) {
                    float xj = x[3 * (long long)j + c];
                    float xk = x[3 * (long long)k + c];
                    float xi = x[3 * (long long)i + c];
                    d[u][c]     = xk - xj;
                    d[u][3 + c] = xi - xk;
                }
            }
            #pragma unroll
            for (int c = 0; c < 3; ++c) a[u][c] = attr[3 * ee + c];
        }

        float acc[KPT][9];
        #pragma unroll
        for (int u = 0; u < KPT; ++u)
            #pragma unroll
            for (int i = 0; i < 9; ++i) acc[u][i] = b2[i];

        #pragma unroll 4
        for (int hh = 0; hh < HIDDEN; ++hh) {
            const float bb = b1[hh];
            float w1r[DIN];
            #pragma unroll
            for (int r = 0; r < DIN; ++r) w1r[r] = W1[r * HIDDEN + hh];
            float w2r[9];
            #pragma unroll
            for (int i = 0; i < 9; ++i) w2r[i] = W2[hh * 9 + i];
            #pragma unroll
            for (int u = 0; u < KPT; ++u) {
                float pre = bb;
                #pragma unroll
                for (int r = 0; r < DIN; ++r) pre = fmaf(d[u][r], w1r[r], pre);
                const float h = fmaxf(pre, 0.0f);
                #pragma unroll
                for (int i = 0; i < 9; ++i) acc[u][i] = fmaf(h, w2r[i], acc[u][i]);
            }
        }

        #pragma unroll
        for (int u = 0; u < KPT; ++u) {
            if (!valid[u]) continue;
            float y0 = fmaf(acc[u][0], a[u][0], fmaf(acc[u][1], a[u][1], acc[u][2] * a[u][2]));
            float y1 = fmaf(acc[u][3], a[u][0], fmaf(acc[u][4], a[u][1], acc[u][5] * a[u][2]));
            float y2 = fmaf(acc[u][6], a[u][0], fmaf(acc[u][7], a[u][1], acc[u][8] * a[u][2]));
            int b = dst[u] >> NPB_SHIFT;
            int r = atomicAdd(&s_rank[b], 1);            // LDS, fast
            int slot = s_base[b] + r;
            if (slot < cap)                              // ~12-sigma safety clamp
                records[(size_t)b * cap + slot] =
                    make_float4(y0, y1, y2, __int_as_float(dst[u]));
        }
    }
}

// ---------------- Phase 2a: per-(bucket,sub) partial LDS tiles ----------------
__global__ __launch_bounds__(256) void p2_partial(
    const float4* __restrict__ records, const int* __restrict__ gcount,
    int cap, float* __restrict__ partials)
{
    __shared__ float s_acc[TILE_F];   // 6 KB
    const int b = blockIdx.x / SSPLIT;
    const int s = blockIdx.x % SSPLIT;
    const int tid = threadIdx.x;

    for (int i = tid; i < TILE_F; i += 256) s_acc[i] = 0.0f;
    __syncthreads();

    int cnt = gcount[b];
    if (cnt > cap) cnt = cap;
    const int chunk = (cnt + SSPLIT - 1) / SSPLIT;
    const int beg = s * chunk;
    const int end = min(beg + chunk, cnt);

    const float4* rb = records + (size_t)b * cap;
    for (int i = beg + tid; i < end; i += 256) {
        float4 r = rb[i];
        int loc = __float_as_int(r.w) - (b << NPB_SHIFT);
        atomicAdd(&s_acc[loc * 3 + 0], r.x);
        atomicAdd(&s_acc[loc * 3 + 1], r.y);
        atomicAdd(&s_acc[loc * 3 + 2], r.z);
    }
    __syncthreads();

    float* pt = partials + (size_t)blockIdx.x * TILE_F;
    for (int i = tid; i < TILE_F; i += 256) pt[i] = s_acc[i];
}

// ---------------- Phase 2b: sum SSPLIT partial tiles -> out ----------------
__global__ __launch_bounds__(256) void p2_final(
    const float4* __restrict__ partials, float4* __restrict__ out, int n4)
{
    int i4 = blockIdx.x * 256 + threadIdx.x;
    if (i4 >= n4) return;
    int b = i4 / TILE_F4;
    int loc = i4 - b * TILE_F4;
    const float4* base = partials + (size_t)b * SSPLIT * TILE_F4 + loc;
    float4 sum = base[0];
    #pragma unroll
    for (int s = 1; s < SSPLIT; ++s) {
        float4 v = base[(size_t)s * TILE_F4];
        sum.x += v.x; sum.y += v.y; sum.z += v.z; sum.w += v.w;
    }
    out[i4] = sum;
}

__global__ void p2_final_tail(const float* __restrict__ partials,
                              float* __restrict__ out, int start, int n)
{
    int idx = start + blockIdx.x * 64 + threadIdx.x;
    if (idx >= n) return;
    int b = idx / TILE_F;
    int loc = idx - b * TILE_F;
    const float* base = partials + (size_t)b * SSPLIT * TILE_F + loc;
    float sum = 0.f;
    #pragma unroll
    for (int s = 0; s < SSPLIT; ++s) sum += base[(size_t)s * TILE_F];
    out[idx] = sum;
}

// ---------------- Fallback p2 (R3): one block per bucket ----------------
__global__ __launch_bounds__(256) void p2_reduce(
    const float4* __restrict__ records, const int* __restrict__ gcount,
    int cap, int n_nodes, float* __restrict__ out)
{
    __shared__ float s_acc[TILE_F];
    const int b = blockIdx.x;
    const int tid = threadIdx.x;
    for (int i = tid; i < TILE_F; i += 256) s_acc[i] = 0.0f;
    __syncthreads();
    int cnt = gcount[b];
    if (cnt > cap) cnt = cap;
    const float4* rb = records + (size_t)b * cap;
    for (int i = tid; i < cnt; i += 256) {
        float4 r = rb[i];
        int loc = __float_as_int(r.w) - (b << NPB_SHIFT);
        atomicAdd(&s_acc[loc * 3 + 0], r.x);
        atomicAdd(&s_acc[loc * 3 + 1], r.y);
        atomicAdd(&s_acc[loc * 3 + 2], r.z);
    }
    __syncthreads();
    const int start = (b << NPB_SHIFT) * 3;
    const int end = min(n_nodes * 3, ((b + 1) << NPB_SHIFT) * 3);
    for (int i = start + tid; i < end; i += 256)
        out[i] = s_acc[i - start];
}

// ---------------- Fallback (R1): direct device atomics ----------------
template <int DIN, int KPT>
__global__ __launch_bounds__(256) void edge_mlp_atomic(
    const float* __restrict__ x,
    const int* __restrict__ edges, long long E,
    const float* __restrict__ attr,
    const float* __restrict__ W1, const float* __restrict__ b1,
    const float* __restrict__ W2, const float* __restrict__ b2,
    float* __restrict__ out)
{
    const int tid = threadIdx.x;
    const long long base = (long long)blockIdx.x * (blockDim.x * KPT) + tid;
    float d[KPT][DIN]; float a[KPT][3]; int dst[KPT]; bool valid[KPT];
    #pragma unroll
    for (int u = 0; u < KPT; ++u) {
        long long e = base + (long long)u * blockDim.x;
        valid[u] = (e < E);
        long long ee = valid[u] ? e : 0;
        if constexpr (DIN == 3) {
            int s = edges[ee]; int t = edges[E + ee]; dst[u] = t;
            #pragma unroll
            for (int c = 0; c < 3; ++c)
                d[u][c] = x[3 * (long long)s + c] - x[3 * (long long)t + c];
        } else {
            int j = edges[ee]; int k = edges[E + ee]; int i = edges[2 * E + ee];
            dst[u] = i;
            #pragma unroll
            for (int c = 0; c < 3; ++c) {
                float xj = x[3 * (long long)j + c];
                float xk = x[3 * (long long)k + c];
                float xi = x[3 * (long long)i + c];
                d[u][c] = xk - xj; d[u][3 + c] = xi - xk;
            }
        }
        #pragma unroll
        for (int c = 0; c < 3; ++c) a[u][c] = attr[3 * ee + c];
    }
    float acc[KPT][9];
    #pragma unroll
    for (int u = 0; u < KPT; ++u)
        #pragma unroll
        for (int i = 0; i < 9; ++i) acc[u][i] = b2[i];
    #pragma unroll 4
    for (int hh = 0; hh < HIDDEN; ++hh) {
        const float bb = b1[hh];
        float w1r[DIN];
        #pragma unroll
        for (int r = 0; r < DIN; ++r) w1r[r] = W1[r * HIDDEN + hh];
        float w2r[9];
        #pragma unroll
        for (int i = 0; i < 9; ++i) w2r[i] = W2[hh * 9 + i];
        #pragma unroll
        for (int u = 0; u < KPT; ++u) {
            float pre = bb;
            #pragma unroll
            for (int r = 0; r < DIN; ++r) pre = fmaf(d[u][r], w1r[r], pre);
            const float h = fmaxf(pre, 0.0f);
            #pragma unroll
            for (int i = 0; i < 9; ++i) acc[u][i] = fmaf(h, w2r[i], acc[u][i]);
        }
    }
    #pragma unroll
    for (int u = 0; u < KPT; ++u) {
        if (!valid[u]) continue;
        float* o = out + 3 * (long long)dst[u];
        #pragma unroll
        for (int i = 0; i < 3; ++i) {
            float y = fmaf(acc[u][3 * i + 0], a[u][0],
                      fmaf(acc[u][3 * i + 1], a[u][1],
                           acc[u][3 * i + 2] * a[u][2]));
            atomicAdd(&o[i], y);
        }
    }
}

extern "C" void kernel_launch(void* const* d_in, const int* in_sizes, int n_in,
                              void* d_out, int out_size, void* d_ws, size_t ws_size,
                              hipStream_t stream)
{
    const float* x  = (const float*)d_in[0];
    const int*   e2 = (const int*)d_in[1];
    const int*   e3 = (const int*)d_in[2];
    const int*   es = (const int*)d_in[3];
    const float* a2 = (const float*)d_in[5];
    const float* a3 = (const float*)d_in[6];
    const float* as = (const float*)d_in[7];
    const float* W1_2b = (const float*)d_in[9];
    const float* b1_2b = (const float*)d_in[10];
    const float* W2_2b = (const float*)d_in[11];
    const float* b2_2b = (const float*)d_in[12];
    const float* W1_3b = (const float*)d_in[13];
    const float* b1_3b = (const float*)d_in[14];
    const float* W2_3b = (const float*)d_in[15];
    const float* b2_3b = (const float*)d_in[16];
    const float* W1_s  = (const float*)d_in[17];
    const float* b1_s  = (const float*)d_in[18];
    const float* W2_s  = (const float*)d_in[19];
    const float* b2_s  = (const float*)d_in[20];

    const long long E2 = in_sizes[1] / 2;
    const long long E3 = in_sizes[2] / 3;
    const long long ES = in_sizes[3] / 2;
    const long long Etot = E2 + E3 + ES;
    const int n_nodes = out_size / 3;
    const int nbuckets = (n_nodes + NPB - 1) >> NPB_SHIFT;

    float* out = (float*)d_out;

    // ws layout: [gcount 4KB][partials nbuckets*S*TILE_F*4B][records]
    const size_t off_part = 4096;
    const size_t part_bytes = (size_t)nbuckets * SSPLIT * TILE_F * sizeof(float);
    long long mean_per_bucket = (Etot + nbuckets - 1) / nbuckets;
    long long min_cap = mean_per_bucket + 1600;

    constexpr int P1_BLK = 1024, P1_KPT = 2;
    const long long p1_tile = (long long)P1_BLK * P1_KPT;
    int g2 = (int)((E2 + p1_tile - 1) / p1_tile);
    int g3 = (int)((E3 + p1_tile - 1) / p1_tile);
    int gs = (int)((ES + p1_tile - 1) / p1_tile);

    // try: split-p2 layout; else R3 layout; else atomic fallback
    long long cap_avail_split =
        ((long long)ws_size - (long long)off_part - (long long)part_bytes) /
        ((long long)nbuckets * 16);
    long long cap_avail_plain =
        ((long long)ws_size - (long long)off_part) / ((long long)nbuckets * 16);

    if (nbuckets <= NB_MAX && cap_avail_split >= min_cap) {
        long long capL = min_cap + 4096;
        if (capL > cap_avail_split) capL = cap_avail_split;
        int cap = (int)capL;
        int* gcount = (int*)d_ws;
        float* partials = (float*)((char*)d_ws + off_part);
        float4* records = (float4*)((char*)d_ws + off_part + part_bytes);

        hipMemsetAsync(gcount, 0, NB_MAX * sizeof(int), stream);

        if (g2 > 0)
            p1_edge_kernel<3><<<g2, P1_BLK, 0, stream>>>(
                x, e2, E2, a2, W1_2b, b1_2b, W2_2b, b2_2b, records, gcount, cap);
        if (g3 > 0)
            p1_edge_kernel<6><<<g3, P1_BLK, 0, stream>>>(
                x, e3, E3, a3, W1_3b, b1_3b, W2_3b, b2_3b, records, gcount, cap);
        if (gs > 0)
            p1_edge_kernel<3><<<gs, P1_BLK, 0, stream>>>(
                x, es, ES, as, W1_s, b1_s, W2_s, b2_s, records, gcount, cap);

        p2_partial<<<nbuckets * SSPLIT, 256, 0, stream>>>(records, gcount, cap, partials);

        int n4 = out_size / 4;
        int tail = out_size - n4 * 4;
        if (n4 > 0)
            p2_final<<<(n4 + 255) / 256, 256, 0, stream>>>(
                (const float4*)partials, (float4*)out, n4);
        if (tail > 0)
            p2_final_tail<<<1, 64, 0, stream>>>(partials, out, n4 * 4, out_size);
    } else if (nbuckets <= NB_MAX && cap_avail_plain >= min_cap) {
        long long capL = min_cap + 4096;
        if (capL > cap_avail_plain) capL = cap_avail_plain;
        int cap = (int)capL;
        int* gcount = (int*)d_ws;
        float4* records = (float4*)((char*)d_ws + off_part);

        hipMemsetAsync(gcount, 0, NB_MAX * sizeof(int), stream);

        if (g2 > 0)
            p1_edge_kernel<3><<<g2, P1_BLK, 0, stream>>>(
                x, e2, E2, a2, W1_2b, b1_2b, W2_2b, b2_2b, records, gcount, cap);
        if (g3 > 0)
            p1_edge_kernel<6><<<g3, P1_BLK, 0, stream>>>(
                x, e3, E3, a3, W1_3b, b1_3b, W2_3b, b2_3b, records, gcount, cap);
        if (gs > 0)
            p1_edge_kernel<3><<<gs, P1_BLK, 0, stream>>>(
                x, es, ES, as, W1_s, b1_s, W2_s, b2_s, records, gcount, cap);

        p2_reduce<<<nbuckets, 256, 0, stream>>>(records, gcount, cap, n_nodes, out);
    } else {
        hipMemsetAsync(out, 0, (size_t)out_size * sizeof(float), stream);
        constexpr int BLK = 256, KPT = 4;
        const long long per_blk = (long long)BLK * KPT;
        int a2g = (int)((E2 + per_blk - 1) / per_blk);
        int a3g = (int)((E3 + per_blk - 1) / per_blk);
        int asg = (int)((ES + per_blk - 1) / per_blk);
        if (a2g > 0)
            edge_mlp_atomic<3, KPT><<<a2g, BLK, 0, stream>>>(
                x, e2, E2, a2, W1_2b, b1_2b, W2_2b, b2_2b, out);
        if (a3g > 0)
            edge_mlp_atomic<6, KPT><<<a3g, BLK, 0, stream>>>(
                x, e3, E3, a3, W1_3b, b1_3b, W2_3b, b2_3b, out);
        if (asg > 0)
            edge_mlp_atomic<3, KPT><<<asg, BLK, 0, stream>>>(
                x, es, ES, as, W1_s, b1_s, W2_s, b2_s, out);
    }
}